// Round 1
// baseline (477.064 us; speedup 1.0000x reference)
//
#include <hip/hip_runtime.h>

#define N_NODES 8192
#define FDIM 128
#define NEG_SLOPE 0.2f
#define CAP 2048

// ---------------- Kernel A: Wh = h @ W.T (fp32) ----------------
// block = 256 threads, 32 rows per block, W^T staged in LDS (padded).
__global__ __launch_bounds__(256) void wh_gemm_kernel(
    const float* __restrict__ h, const float* __restrict__ W,
    float* __restrict__ Wh) {
  __shared__ float Wt[FDIM * 129];   // Wt[k*129 + o] = W[o][k]
  __shared__ float rows[32 * FDIM];
  const int t = threadIdx.x;
  const int base = blockIdx.x * 32;
  for (int it = 0; it < 64; ++it) {
    int idx = t + 256 * it;          // idx = o*128 + k
    int o = idx >> 7, k = idx & 127;
    Wt[k * 129 + o] = W[idx];
  }
  for (int it = 0; it < 16; ++it) {
    int idx = t + 256 * it;          // idx = rloc*128 + col
    rows[idx] = h[(size_t)base * FDIM + idx];
  }
  __syncthreads();
  const int o = t & 127;
  const int rhalf = t >> 7;
  float acc[16];
#pragma unroll
  for (int kk = 0; kk < 16; ++kk) acc[kk] = 0.f;
  for (int k = 0; k < FDIM; ++k) {
    float wv = Wt[k * 129 + o];
#pragma unroll
    for (int kk = 0; kk < 16; ++kk)
      acc[kk] += rows[(rhalf * 16 + kk) * FDIM + k] * wv;
  }
#pragma unroll
  for (int kk = 0; kk < 16; ++kk) {
    int r = base + rhalf * 16 + kk;
    Wh[(size_t)r * FDIM + o] = acc[kk];
  }
}

// ---------------- Kernel C1: s1 = Wh@a1, s2 = Wh@a2 ----------------
// one wave per row (4 rows / 256-thread block)
__global__ __launch_bounds__(256) void scores_kernel(
    const float* __restrict__ Wh, const float* __restrict__ a,
    float* __restrict__ s1, float* __restrict__ s2) {
  const int t = threadIdx.x;
  const int lane = t & 63;
  const int wave = t >> 6;
  const int row = blockIdx.x * 4 + wave;
  float v0 = Wh[(size_t)row * FDIM + lane];
  float v1 = Wh[(size_t)row * FDIM + 64 + lane];
  float d1 = v0 * a[lane] + v1 * a[64 + lane];
  float d2 = v0 * a[FDIM + lane] + v1 * a[FDIM + 64 + lane];
  for (int off = 32; off; off >>= 1) {
    d1 += __shfl_down(d1, off);
    d2 += __shfl_down(d2, off);
  }
  if (lane == 0) { s1[row] = d1; s2[row] = d2; }
}

// ---------------- Kernel C2: S[f] = sum_i Wh[i][f] ----------------
// 32 blocks x 256 rows each; S must be zeroed (memset) before launch.
__global__ __launch_bounds__(256) void colsum_kernel(
    const float* __restrict__ Wh, float* __restrict__ S) {
  __shared__ float sh[2][FDIM];
  const int t = threadIdx.x;
  const int f = t & 127, seg = t >> 7;
  float acc = 0.f;
  const size_t rbase = (size_t)blockIdx.x * 256 + (size_t)seg * 128;
  for (int k = 0; k < 128; ++k)
    acc += Wh[(rbase + k) * FDIM + f];
  sh[seg][f] = acc;
  __syncthreads();
  if (seg == 0) atomicAdd(&S[f], sh[0][f] + sh[1][f]);
}

// ---------------- Kernel B: per-row softmax + sparse gather ----------------
// one block (256 threads = 4 waves) per row i.
// pass 1: scan adj row (float4, coalesced), ballot-compact nonzero j + e-val
// pass 2: exp/sum from LDS (no adj re-read)
// pass 3: out_i[f] = [sum_nbr (p-em)*Wh[j][f] + em*S[f]] / l
__global__ __launch_bounds__(256) void gat_row_kernel(
    const float* __restrict__ adj, const float* __restrict__ Wh,
    const float* __restrict__ s1, const float* __restrict__ s2,
    const float* __restrict__ S, float* __restrict__ out) {
  const int i = blockIdx.x;
  const int t = threadIdx.x;
  const int lane = t & 63;
  const int wave = t >> 6;
  __shared__ int nbr[CAP];
  __shared__ float pv[CAP];
  __shared__ int cnt_s;
  __shared__ float red[4];
  __shared__ float m_sh, l_sh, em_sh;
  __shared__ float fpart[2][FDIM];
  if (t == 0) cnt_s = 0;
  __syncthreads();
  const float s1i = s1[i];
  const float4* __restrict__ arow = (const float4*)(adj + (size_t)i * N_NODES);
  const float4* __restrict__ s2v = (const float4*)s2;
  float lmax = -1e30f;
  for (int it = 0; it < N_NODES / 1024; ++it) {
    const int j4 = it * 256 + t;
    float4 av = arow[j4];
    float4 sv = s2v[j4];
    float avv[4] = {av.x, av.y, av.z, av.w};
    float svv[4] = {sv.x, sv.y, sv.z, sv.w};
    float ecand[4];
    bool pred[4];
#pragma unroll
    for (int c = 0; c < 4; ++c) {
      float e = s1i + svv[c];
      e = e > 0.f ? e : NEG_SLOPE * e;
      ecand[c] = e;
      pred[c] = (avv[c] != 0.f);
      if (pred[c]) lmax = fmaxf(lmax, e);
    }
#pragma unroll
    for (int c = 0; c < 4; ++c) {
      unsigned long long b = __ballot(pred[c]);
      int prefix = __popcll(b & ((1ull << lane) - 1ull));
      int bse = 0;
      if (lane == 0) bse = atomicAdd(&cnt_s, (int)__popcll(b));
      bse = __shfl(bse, 0);
      if (pred[c]) {
        int pos = bse + prefix;
        if (pos < CAP) { nbr[pos] = j4 * 4 + c; pv[pos] = ecand[c]; }
      }
    }
  }
  // block max
  for (int off = 32; off; off >>= 1) lmax = fmaxf(lmax, __shfl_down(lmax, off));
  if (lane == 0) red[wave] = lmax;
  __syncthreads();
  if (t == 0) {
    float m = fmaxf(fmaxf(red[0], red[1]), fmaxf(red[2], red[3]));
    int cnt = cnt_s;
    if (cnt > CAP) cnt = CAP;  // never in practice (mean 410, CAP 2048)
    cnt_s = cnt;
    if (cnt < N_NODES) m = fmaxf(m, 0.f);  // zeros contribute z=0 to the max
    m_sh = m;
  }
  __syncthreads();
  const float m = m_sh;
  const int cnt = cnt_s;
  // exp + sum (pv: e -> p = exp(e-m))
  float lsum = 0.f;
  for (int k = t; k < cnt; k += 256) {
    float p = __expf(pv[k] - m);
    pv[k] = p;
    lsum += p;
  }
  for (int off = 32; off; off >>= 1) lsum += __shfl_down(lsum, off);
  __syncthreads();  // red[] reads by t0 above done; pv writes visible after next barrier
  if (lane == 0) red[wave] = lsum;
  __syncthreads();
  if (t == 0) {
    float em = __expf(-m);
    float l = red[0] + red[1] + red[2] + red[3] + (float)(N_NODES - cnt) * em;
    l_sh = l;
    em_sh = em;
  }
  __syncthreads();
  const float l = l_sh, em = em_sh;
  // gather-accumulate: 2 groups of 128 threads, thread owns feature f
  const int f = t & 127, g = t >> 7;
  float a0 = 0.f, a1 = 0.f, a2 = 0.f, a3 = 0.f;
  int k = g;
  for (; k + 6 < cnt; k += 8) {
    a0 += (pv[k]     - em) * Wh[(size_t)nbr[k]     * FDIM + f];
    a1 += (pv[k + 2] - em) * Wh[(size_t)nbr[k + 2] * FDIM + f];
    a2 += (pv[k + 4] - em) * Wh[(size_t)nbr[k + 4] * FDIM + f];
    a3 += (pv[k + 6] - em) * Wh[(size_t)nbr[k + 6] * FDIM + f];
  }
  for (; k < cnt; k += 2)
    a0 += (pv[k] - em) * Wh[(size_t)nbr[k] * FDIM + f];
  fpart[g][f] = a0 + a1 + a2 + a3;
  __syncthreads();
  if (g == 0) {
    float o = (fpart[0][f] + fpart[1][f] + em * S[f]) / l;
    out[(size_t)i * FDIM + f] = o;
  }
}

extern "C" void kernel_launch(void* const* d_in, const int* in_sizes, int n_in,
                              void* d_out, int out_size, void* d_ws, size_t ws_size,
                              hipStream_t stream) {
  const float* h   = (const float*)d_in[0];
  const float* adj = (const float*)d_in[1];
  const float* W   = (const float*)d_in[2];
  const float* a   = (const float*)d_in[3];
  float* out = (float*)d_out;
  // workspace layout (fp32): Wh[N*F] | s1[N] | s2[N] | S[F]
  float* Wh = (float*)d_ws;
  float* s1 = Wh + (size_t)N_NODES * FDIM;
  float* s2 = s1 + N_NODES;
  float* S  = s2 + N_NODES;

  hipLaunchKernelGGL(wh_gemm_kernel, dim3(N_NODES / 32), dim3(256), 0, stream,
                     h, W, Wh);
  hipLaunchKernelGGL(scores_kernel, dim3(N_NODES / 4), dim3(256), 0, stream,
                     Wh, a, s1, s2);
  hipMemsetAsync(S, 0, FDIM * sizeof(float), stream);
  hipLaunchKernelGGL(colsum_kernel, dim3(32), dim3(256), 0, stream, Wh, S);
  hipLaunchKernelGGL(gat_row_kernel, dim3(N_NODES), dim3(256), 0, stream,
                     adj, Wh, s1, s2, S, out);
}

// Round 2
// 467.841 us; speedup vs baseline: 1.0197x; 1.0197x over previous
//
#include <hip/hip_runtime.h>

#define N_NODES 8192
#define FDIM 128
#define NEG_SLOPE 0.2f
#define SEG 512   // per-wave neighbor capacity (mean ~102 per segment, 40 sigma headroom)

// ---------------- Kernel A: Wh = h @ W.T (fp32) ----------------
// block = 256 threads, 32 rows per block, W^T staged in LDS (padded).
// rows stride 132: kk-stride bank offset = 4*kk % 32 -> 2-way conflict (free).
__global__ __launch_bounds__(256) void wh_gemm_kernel(
    const float* __restrict__ h, const float* __restrict__ W,
    float* __restrict__ Wh) {
  __shared__ float Wt[FDIM * 129];   // Wt[k*129 + o] = W[o][k]
  __shared__ float rows[32 * 132];   // rows[r*132 + k]
  const int t = threadIdx.x;
  const int base = blockIdx.x * 32;
  for (int it = 0; it < 64; ++it) {
    int idx = t + 256 * it;          // idx = o*128 + k
    int o = idx >> 7, k = idx & 127;
    Wt[k * 129 + o] = W[idx];
  }
  for (int it = 0; it < 16; ++it) {
    int idx = t + 256 * it;          // idx = rloc*128 + col
    int rloc = idx >> 7, col = idx & 127;
    rows[rloc * 132 + col] = h[(size_t)base * FDIM + idx];
  }
  __syncthreads();
  const int o = t & 127;
  const int rhalf = t >> 7;
  float acc[16];
#pragma unroll
  for (int kk = 0; kk < 16; ++kk) acc[kk] = 0.f;
  for (int k = 0; k < FDIM; ++k) {
    float wv = Wt[k * 129 + o];
#pragma unroll
    for (int kk = 0; kk < 16; ++kk)
      acc[kk] += rows[(rhalf * 16 + kk) * 132 + k] * wv;
  }
#pragma unroll
  for (int kk = 0; kk < 16; ++kk) {
    int r = base + rhalf * 16 + kk;
    Wh[(size_t)r * FDIM + o] = acc[kk];
  }
}

// ---------------- Kernel C1: s1 = Wh@a1, s2 = Wh@a2 ----------------
__global__ __launch_bounds__(256) void scores_kernel(
    const float* __restrict__ Wh, const float* __restrict__ a,
    float* __restrict__ s1, float* __restrict__ s2) {
  const int t = threadIdx.x;
  const int lane = t & 63;
  const int wave = t >> 6;
  const int row = blockIdx.x * 4 + wave;
  float v0 = Wh[(size_t)row * FDIM + lane];
  float v1 = Wh[(size_t)row * FDIM + 64 + lane];
  float d1 = v0 * a[lane] + v1 * a[64 + lane];
  float d2 = v0 * a[FDIM + lane] + v1 * a[FDIM + 64 + lane];
  for (int off = 32; off; off >>= 1) {
    d1 += __shfl_down(d1, off);
    d2 += __shfl_down(d2, off);
  }
  if (lane == 0) { s1[row] = d1; s2[row] = d2; }
}

// ---------------- Kernel C2: S[f] = sum_i Wh[i][f] ----------------
// 64 blocks x 128 rows each; S zeroed via memsetAsync before launch.
__global__ __launch_bounds__(256) void colsum_kernel(
    const float* __restrict__ Wh, float* __restrict__ S) {
  __shared__ float sh[2][FDIM];
  const int t = threadIdx.x;
  const int f = t & 127, seg = t >> 7;
  float acc = 0.f;
  const size_t rbase = (size_t)blockIdx.x * 128 + (size_t)seg * 64;
  for (int k = 0; k < 64; ++k)
    acc += Wh[(rbase + k) * FDIM + f];
  sh[seg][f] = acc;
  __syncthreads();
  if (seg == 0) atomicAdd(&S[f], sh[0][f] + sh[1][f]);
}

// ---------------- Kernel B: per-row softmax + sparse gather ----------------
// one block (256 threads = 4 waves) per row i.
// pass 1: scan adj row (float4 coalesced); each WAVE compacts its hits into
//         its OWN LDS segment (register base counter — no atomics, no shfl).
// pass 2: each wave exps its own segment; block-reduce m and l.
// pass 3: wave w gathers over segment w; lane owns features [2*lane, 2*lane+1].
__global__ __launch_bounds__(256) void gat_row_kernel(
    const float* __restrict__ adj, const float* __restrict__ Wh,
    const float* __restrict__ s1, const float* __restrict__ s2,
    const float* __restrict__ S, float* __restrict__ out) {
  const int i = blockIdx.x;
  const int t = threadIdx.x;
  const int lane = t & 63;
  const int wave = t >> 6;
  __shared__ int nbr[4 * SEG];
  __shared__ float pv[4 * SEG];
  __shared__ int counts[4];
  __shared__ float red[4];
  __shared__ float m_sh, l_sh, em_sh;
  __shared__ float fpart[4][FDIM];

  const float s1i = s1[i];
  const float4* __restrict__ arow = (const float4*)(adj + (size_t)i * N_NODES);
  const float4* __restrict__ s2v = (const float4*)s2;
  int* __restrict__ mynbr = nbr + wave * SEG;
  float* __restrict__ mypv = pv + wave * SEG;
  const unsigned long long lmask = (1ull << lane) - 1ull;

  int base = 0;            // wave-uniform running count (ballot is uniform)
  float lmax = -1e30f;
  for (int it = 0; it < N_NODES / 1024; ++it) {
    const int j4 = it * 256 + t;
    float4 av = arow[j4];
    float4 sv = s2v[j4];
    float avv[4] = {av.x, av.y, av.z, av.w};
    float svv[4] = {sv.x, sv.y, sv.z, sv.w};
    float ecand[4];
    bool pred[4];
#pragma unroll
    for (int c = 0; c < 4; ++c) {
      float e = s1i + svv[c];
      e = e > 0.f ? e : NEG_SLOPE * e;
      ecand[c] = e;
      pred[c] = (avv[c] != 0.f);
      if (pred[c]) lmax = fmaxf(lmax, e);
    }
#pragma unroll
    for (int c = 0; c < 4; ++c) {
      unsigned long long b = __ballot(pred[c]);
      if (pred[c]) {
        int pos = base + (int)__popcll(b & lmask);
        if (pos < SEG) { mynbr[pos] = j4 * 4 + c; mypv[pos] = ecand[c]; }
      }
      base += (int)__popcll(b);
    }
  }
  if (lane == 0) counts[wave] = base < SEG ? base : SEG;
  for (int off = 32; off; off >>= 1) lmax = fmaxf(lmax, __shfl_down(lmax, off));
  if (lane == 0) red[wave] = lmax;
  __syncthreads();
  if (t == 0) {
    float m = fmaxf(fmaxf(red[0], red[1]), fmaxf(red[2], red[3]));
    int cnt = counts[0] + counts[1] + counts[2] + counts[3];
    if (cnt < N_NODES) m = fmaxf(m, 0.f);  // adj==0 entries contribute z=0
    m_sh = m;
  }
  __syncthreads();
  const float m = m_sh;
  const int mycnt = counts[wave];
  // exp + per-wave sum over own segment
  float lsum = 0.f;
  for (int k = lane; k < mycnt; k += 64) {
    float p = __expf(mypv[k] - m);
    mypv[k] = p;
    lsum += p;
  }
  for (int off = 32; off; off >>= 1) lsum += __shfl_down(lsum, off);
  if (lane == 0) red[wave] = lsum;
  __syncthreads();
  if (t == 0) {
    int cnt = counts[0] + counts[1] + counts[2] + counts[3];
    float em = __expf(-m);
    l_sh = red[0] + red[1] + red[2] + red[3] + (float)(N_NODES - cnt) * em;
    em_sh = em;
  }
  __syncthreads();
  const float l = l_sh, em = em_sh;
  // gather: wave w walks its own segment; lane loads Wh[j] as float2
  const float2* __restrict__ Wh2 = (const float2*)Wh;
  float a0x = 0.f, a0y = 0.f, a1x = 0.f, a1y = 0.f;
  int k = 0;
  for (; k + 1 < mycnt; k += 2) {
    float w0 = mypv[k] - em, w1 = mypv[k + 1] - em;
    int j0 = mynbr[k], j1 = mynbr[k + 1];
    float2 v0 = Wh2[(size_t)j0 * 64 + lane];
    float2 v1 = Wh2[(size_t)j1 * 64 + lane];
    a0x += w0 * v0.x; a0y += w0 * v0.y;
    a1x += w1 * v1.x; a1y += w1 * v1.y;
  }
  if (k < mycnt) {
    float w0 = mypv[k] - em;
    float2 v0 = Wh2[(size_t)mynbr[k] * 64 + lane];
    a0x += w0 * v0.x; a0y += w0 * v0.y;
  }
  fpart[wave][2 * lane]     = a0x + a1x;
  fpart[wave][2 * lane + 1] = a0y + a1y;
  __syncthreads();
  if (t < FDIM) {
    int f = t;
    float o = (fpart[0][f] + fpart[1][f] + fpart[2][f] + fpart[3][f]
               + em * S[f]) / l;
    out[(size_t)i * FDIM + f] = o;
  }
}

extern "C" void kernel_launch(void* const* d_in, const int* in_sizes, int n_in,
                              void* d_out, int out_size, void* d_ws, size_t ws_size,
                              hipStream_t stream) {
  const float* h   = (const float*)d_in[0];
  const float* adj = (const float*)d_in[1];
  const float* W   = (const float*)d_in[2];
  const float* a   = (const float*)d_in[3];
  float* out = (float*)d_out;
  // workspace layout (fp32): Wh[N*F] | s1[N] | s2[N] | S[F]
  float* Wh = (float*)d_ws;
  float* s1 = Wh + (size_t)N_NODES * FDIM;
  float* s2 = s1 + N_NODES;
  float* S  = s2 + N_NODES;

  hipLaunchKernelGGL(wh_gemm_kernel, dim3(N_NODES / 32), dim3(256), 0, stream,
                     h, W, Wh);
  hipLaunchKernelGGL(scores_kernel, dim3(N_NODES / 4), dim3(256), 0, stream,
                     Wh, a, s1, s2);
  hipMemsetAsync(S, 0, FDIM * sizeof(float), stream);
  hipLaunchKernelGGL(colsum_kernel, dim3(64), dim3(256), 0, stream, Wh, S);
  hipLaunchKernelGGL(gat_row_kernel, dim3(N_NODES), dim3(256), 0, stream,
                     adj, Wh, s1, s2, S, out);
}

// Round 3
// 453.864 us; speedup vs baseline: 1.0511x; 1.0308x over previous
//
#include <hip/hip_runtime.h>

#define N_NODES 8192
#define FDIM 128
#define NEG_SLOPE 0.2f
#define SEG 512   // per-wave neighbor capacity (mean ~102, 40 sigma headroom)

// ---------------- Kernel A: Wh = h @ W.T (fp32) + colsum S ----------------
// 256 blocks x 256 thr; block = 32 rows x 128 cols; thread = 4 rows x 4 cols.
// Per k: 1 ds_read_b128 (Wt) + 4 broadcast ds_read_b32 (rows) -> 16 FMA.
__global__ __launch_bounds__(256) void wh_fused_kernel(
    const float* __restrict__ h, const float* __restrict__ W,
    float* __restrict__ Wh, float* __restrict__ S) {
  __shared__ float Wt[FDIM * 132];   // Wt[k*132+o] = W[o][k]; 132: keeps 16B align
  __shared__ float rows[32 * 132];   // rows[r*132+k]; reused as colsum scratch
  const int t = threadIdx.x;
  const int base = blockIdx.x * 32;
  for (int it = 0; it < 64; ++it) {
    int idx = t + 256 * it;          // idx = o*128+k
    int o = idx >> 7, k = idx & 127;
    Wt[k * 132 + o] = W[idx];
  }
  for (int it = 0; it < 16; ++it) {
    int idx = t + 256 * it;          // idx = r*128+col
    int r = idx >> 7, col = idx & 127;
    rows[r * 132 + col] = h[(size_t)base * FDIM + idx];
  }
  __syncthreads();
  const int c4 = (t & 31) * 4;       // cols c4..c4+3
  const int g = t >> 5;              // rows 4g..4g+3
  float acc[4][4];
#pragma unroll
  for (int rr = 0; rr < 4; ++rr)
#pragma unroll
    for (int cc = 0; cc < 4; ++cc) acc[rr][cc] = 0.f;
  for (int k = 0; k < FDIM; ++k) {
    float4 wv = *(const float4*)&Wt[k * 132 + c4];
    float rv[4];
#pragma unroll
    for (int rr = 0; rr < 4; ++rr) rv[rr] = rows[(4 * g + rr) * 132 + k];
#pragma unroll
    for (int rr = 0; rr < 4; ++rr) {
      acc[rr][0] += rv[rr] * wv.x;
      acc[rr][1] += rv[rr] * wv.y;
      acc[rr][2] += rv[rr] * wv.z;
      acc[rr][3] += rv[rr] * wv.w;
    }
  }
#pragma unroll
  for (int rr = 0; rr < 4; ++rr) {
    int r = base + 4 * g + rr;
    *(float4*)&Wh[(size_t)r * FDIM + c4] =
        make_float4(acc[rr][0], acc[rr][1], acc[rr][2], acc[rr][3]);
  }
  // ---- colsum epilogue ----
  __syncthreads();                   // all waves done reading rows[]
  float4 cs = make_float4(acc[0][0] + acc[1][0] + acc[2][0] + acc[3][0],
                          acc[0][1] + acc[1][1] + acc[2][1] + acc[3][1],
                          acc[0][2] + acc[1][2] + acc[2][2] + acc[3][2],
                          acc[0][3] + acc[1][3] + acc[2][3] + acc[3][3]);
  *(float4*)&rows[g * FDIM + c4] = cs;   // scratch[g][col]
  __syncthreads();
  if (t < FDIM) {
    float s = 0.f;
#pragma unroll
    for (int gg = 0; gg < 8; ++gg) s += rows[gg * FDIM + t];
    atomicAdd(&S[t], s);
  }
}

// ---------------- Kernel C1: s1 = Wh@a1, s2 = Wh@a2 ----------------
__global__ __launch_bounds__(256) void scores_kernel(
    const float* __restrict__ Wh, const float* __restrict__ a,
    float* __restrict__ s1, float* __restrict__ s2) {
  const int t = threadIdx.x;
  const int lane = t & 63;
  const int wave = t >> 6;
  const int row = blockIdx.x * 4 + wave;
  float v0 = Wh[(size_t)row * FDIM + lane];
  float v1 = Wh[(size_t)row * FDIM + 64 + lane];
  float d1 = v0 * a[lane] + v1 * a[64 + lane];
  float d2 = v0 * a[FDIM + lane] + v1 * a[FDIM + 64 + lane];
  for (int off = 32; off; off >>= 1) {
    d1 += __shfl_down(d1, off);
    d2 += __shfl_down(d2, off);
  }
  if (lane == 0) { s1[row] = d1; s2[row] = d2; }
}

// ---------------- Kernel B: per-row softmax + sparse gather ----------------
// one block (4 waves) per row i.
// scan: prefetched float4 stream over adj row; per-wave compaction of
//       (e, j) pairs into own LDS segment (ds_write_b64, no atomics).
// gather: half-wave per neighbor row, float4 Wh loads, exp fused in
//         (each pair's exp computed by 32 lanes; wave-sum/32 is exact).
__global__ __launch_bounds__(256) void gat_row_kernel(
    const float* __restrict__ adj, const float* __restrict__ Wh,
    const float* __restrict__ s1, const float* __restrict__ s2,
    const float* __restrict__ S, float* __restrict__ out) {
  const int i = blockIdx.x;
  const int t = threadIdx.x;
  const int lane = t & 63;
  const int wave = t >> 6;
  __shared__ float2 pairs[4 * SEG];  // (e, j-as-bits)
  __shared__ int counts[4];
  __shared__ float red[4];           // per-wave max
  __shared__ float red2[4];          // per-wave exp-sum
  __shared__ float fpart[4][FDIM];

  const float s1i = s1[i];
  const float4* __restrict__ arow = (const float4*)(adj + (size_t)i * N_NODES);
  const float4* __restrict__ s2v = (const float4*)s2;
  float2* __restrict__ mypairs = pairs + wave * SEG;
  const unsigned long long lmask = (1ull << lane) - 1ull;

  int cbase = 0;                     // wave-uniform running count
  float lmax = -1e30f;
  float4 av = arow[t], sv = s2v[t];
#pragma unroll
  for (int it = 0; it < N_NODES / 1024; ++it) {
    float4 avn, svn;
    if (it < N_NODES / 1024 - 1) {
      avn = arow[(it + 1) * 256 + t];
      svn = s2v[(it + 1) * 256 + t];
    }
    const int j4 = it * 256 + t;
    float avv[4] = {av.x, av.y, av.z, av.w};
    float svv[4] = {sv.x, sv.y, sv.z, sv.w};
    float ecand[4];
    bool pred[4];
#pragma unroll
    for (int c = 0; c < 4; ++c) {
      float e = s1i + svv[c];
      e = e > 0.f ? e : NEG_SLOPE * e;
      ecand[c] = e;
      pred[c] = (avv[c] != 0.f);
      if (pred[c]) lmax = fmaxf(lmax, e);
    }
#pragma unroll
    for (int c = 0; c < 4; ++c) {
      unsigned long long b = __ballot(pred[c]);
      if (pred[c]) {
        int pos = cbase + (int)__popcll(b & lmask);
        if (pos < SEG)
          mypairs[pos] = make_float2(ecand[c], __int_as_float(j4 * 4 + c));
      }
      cbase += (int)__popcll(b);
    }
    av = avn; sv = svn;
  }
  if (lane == 0) counts[wave] = cbase < SEG ? cbase : SEG;
  for (int off = 32; off; off >>= 1) lmax = fmaxf(lmax, __shfl_down(lmax, off));
  if (lane == 0) red[wave] = lmax;
  __syncthreads();
  // every thread computes m/em/cnt redundantly (no extra barrier)
  const int cnt = counts[0] + counts[1] + counts[2] + counts[3];
  float m = fmaxf(fmaxf(red[0], red[1]), fmaxf(red[2], red[3]));
  if (cnt < N_NODES) m = fmaxf(m, 0.f);  // adj==0 entries contribute z=0
  const float em = __expf(-m);
  // ---- gather over own segment: half-wave per neighbor row ----
  const int mycnt = counts[wave];
  const int half = lane >> 5, lq = lane & 31;
  const float4* __restrict__ Wh4 = (const float4*)Wh;
  float ax = 0.f, ay = 0.f, az = 0.f, aw = 0.f;
  float lsum = 0.f;
  const int nit = (mycnt + 1) >> 1;
  int it = 0;
  for (; it + 1 < nit; it += 2) {
    int p0 = 2 * it + half, p1 = p0 + 2;
    float2 pr0 = mypairs[p0 < mycnt ? p0 : 0];
    float2 pr1 = mypairs[p1 < mycnt ? p1 : 0];
    int j0 = __float_as_int(pr0.y), j1 = __float_as_int(pr1.y);
    float4 v0 = Wh4[(j0 << 5) + lq];
    float4 v1 = Wh4[(j1 << 5) + lq];
    float e0 = __expf(pr0.x - m), e1 = __expf(pr1.x - m);
    bool ok0 = p0 < mycnt, ok1 = p1 < mycnt;
    float w0 = ok0 ? e0 - em : 0.f;
    float w1 = ok1 ? e1 - em : 0.f;
    lsum += (ok0 ? e0 : 0.f) + (ok1 ? e1 : 0.f);
    ax += w0 * v0.x + w1 * v1.x;
    ay += w0 * v0.y + w1 * v1.y;
    az += w0 * v0.z + w1 * v1.z;
    aw += w0 * v0.w + w1 * v1.w;
  }
  if (it < nit) {
    int p0 = 2 * it + half;
    float2 pr0 = mypairs[p0 < mycnt ? p0 : 0];
    int j0 = __float_as_int(pr0.y);
    float4 v0 = Wh4[(j0 << 5) + lq];
    float e0 = __expf(pr0.x - m);
    bool ok0 = p0 < mycnt;
    float w0 = ok0 ? e0 - em : 0.f;
    lsum += ok0 ? e0 : 0.f;
    ax += w0 * v0.x; ay += w0 * v0.y; az += w0 * v0.z; aw += w0 * v0.w;
  }
  // combine odd/even halves (same features, disjoint neighbor subsets)
  ax += __shfl_down(ax, 32);
  ay += __shfl_down(ay, 32);
  az += __shfl_down(az, 32);
  aw += __shfl_down(aw, 32);
  for (int off = 32; off; off >>= 1) lsum += __shfl_down(lsum, off);
  if (lane == 0) red2[wave] = lsum * (1.f / 32.f);  // each pair counted 32x
  if (lane < 32)
    *(float4*)&fpart[wave][4 * lq] = make_float4(ax, ay, az, aw);
  __syncthreads();
  if (t < FDIM) {
    float l = red2[0] + red2[1] + red2[2] + red2[3]
              + (float)(N_NODES - cnt) * em;
    float o = (fpart[0][t] + fpart[1][t] + fpart[2][t] + fpart[3][t]
               + em * S[t]) / l;
    out[(size_t)i * FDIM + t] = o;
  }
}

extern "C" void kernel_launch(void* const* d_in, const int* in_sizes, int n_in,
                              void* d_out, int out_size, void* d_ws, size_t ws_size,
                              hipStream_t stream) {
  const float* h   = (const float*)d_in[0];
  const float* adj = (const float*)d_in[1];
  const float* W   = (const float*)d_in[2];
  const float* a   = (const float*)d_in[3];
  float* out = (float*)d_out;
  // workspace layout (fp32): Wh[N*F] | s1[N] | s2[N] | S[F]
  float* Wh = (float*)d_ws;
  float* s1 = Wh + (size_t)N_NODES * FDIM;
  float* s2 = s1 + N_NODES;
  float* S  = s2 + N_NODES;

  hipMemsetAsync(S, 0, FDIM * sizeof(float), stream);
  hipLaunchKernelGGL(wh_fused_kernel, dim3(N_NODES / 32), dim3(256), 0, stream,
                     h, W, Wh, S);
  hipLaunchKernelGGL(scores_kernel, dim3(N_NODES / 4), dim3(256), 0, stream,
                     Wh, a, s1, s2);
  hipLaunchKernelGGL(gat_row_kernel, dim3(N_NODES), dim3(256), 0, stream,
                     adj, Wh, s1, s2, S, out);
}

// Round 4
// 444.751 us; speedup vs baseline: 1.0727x; 1.0205x over previous
//
#include <hip/hip_runtime.h>

#define N_NODES 8192
#define FDIM 128
#define NEG_SLOPE 0.2f
#define SEG 512   // per-wave neighbor capacity (mean ~102, huge headroom)

// ---------------- Kernel A: Wh = h @ W.T (fp32) + colsum S ----------------
__global__ __launch_bounds__(256) void wh_fused_kernel(
    const float* __restrict__ h, const float* __restrict__ W,
    float* __restrict__ Wh, float* __restrict__ S) {
  __shared__ float Wt[FDIM * 132];   // Wt[k*132+o] = W[o][k]
  __shared__ float rows[32 * 132];   // rows[r*132+k]; reused as colsum scratch
  const int t = threadIdx.x;
  const int base = blockIdx.x * 32;
  for (int it = 0; it < 64; ++it) {
    int idx = t + 256 * it;          // idx = o*128+k
    int o = idx >> 7, k = idx & 127;
    Wt[k * 132 + o] = W[idx];
  }
  for (int it = 0; it < 16; ++it) {
    int idx = t + 256 * it;          // idx = r*128+col
    int r = idx >> 7, col = idx & 127;
    rows[r * 132 + col] = h[(size_t)base * FDIM + idx];
  }
  __syncthreads();
  const int c4 = (t & 31) * 4;
  const int g = t >> 5;
  float acc[4][4];
#pragma unroll
  for (int rr = 0; rr < 4; ++rr)
#pragma unroll
    for (int cc = 0; cc < 4; ++cc) acc[rr][cc] = 0.f;
  for (int k = 0; k < FDIM; ++k) {
    float4 wv = *(const float4*)&Wt[k * 132 + c4];
    float rv[4];
#pragma unroll
    for (int rr = 0; rr < 4; ++rr) rv[rr] = rows[(4 * g + rr) * 132 + k];
#pragma unroll
    for (int rr = 0; rr < 4; ++rr) {
      acc[rr][0] += rv[rr] * wv.x;
      acc[rr][1] += rv[rr] * wv.y;
      acc[rr][2] += rv[rr] * wv.z;
      acc[rr][3] += rv[rr] * wv.w;
    }
  }
#pragma unroll
  for (int rr = 0; rr < 4; ++rr) {
    int r = base + 4 * g + rr;
    *(float4*)&Wh[(size_t)r * FDIM + c4] =
        make_float4(acc[rr][0], acc[rr][1], acc[rr][2], acc[rr][3]);
  }
  __syncthreads();
  float4 cs = make_float4(acc[0][0] + acc[1][0] + acc[2][0] + acc[3][0],
                          acc[0][1] + acc[1][1] + acc[2][1] + acc[3][1],
                          acc[0][2] + acc[1][2] + acc[2][2] + acc[3][2],
                          acc[0][3] + acc[1][3] + acc[2][3] + acc[3][3]);
  *(float4*)&rows[g * FDIM + c4] = cs;
  __syncthreads();
  if (t < FDIM) {
    float s = 0.f;
#pragma unroll
    for (int gg = 0; gg < 8; ++gg) s += rows[gg * FDIM + t];
    atomicAdd(&S[t], s);
  }
}

// ---------------- Kernel C1: s1 = Wh@a1, s2 = Wh@a2 ----------------
__global__ __launch_bounds__(256) void scores_kernel(
    const float* __restrict__ Wh, const float* __restrict__ a,
    float* __restrict__ s1, float* __restrict__ s2) {
  const int t = threadIdx.x;
  const int lane = t & 63;
  const int wave = t >> 6;
  const int row = blockIdx.x * 4 + wave;
  float v0 = Wh[(size_t)row * FDIM + lane];
  float v1 = Wh[(size_t)row * FDIM + 64 + lane];
  float d1 = v0 * a[lane] + v1 * a[64 + lane];
  float d2 = v0 * a[FDIM + lane] + v1 * a[FDIM + 64 + lane];
  for (int off = 32; off; off >>= 1) {
    d1 += __shfl_down(d1, off);
    d2 += __shfl_down(d2, off);
  }
  if (lane == 0) { s1[row] = d1; s2[row] = d2; }
}

// ---------------- Kernel B: per-row softmax + sparse gather ----------------
// one block (4 waves) per row i.
// scan:   adj ONLY (no s2 stream). 8 float4 loads issued upfront; ballot+
//         mbcnt compaction of j into per-wave LDS segment.
// phase2: e = leakyrelu(s1i + s2[j]) via random 4B gathers (L1-hot), wave max.
// phase3: p = exp(e-m) once per pair, wave sum.   (no cross-wave barrier:
//         each wave touches only its own segment)
// gather: half-wave per pair, float4 Wh loads, 4-deep unroll.
__global__ __launch_bounds__(256) void gat_row_kernel(
    const float* __restrict__ adj, const float* __restrict__ Wh,
    const float* __restrict__ s1, const float* __restrict__ s2,
    const float* __restrict__ S, float* __restrict__ out) {
  const int i = blockIdx.x;
  const int t = threadIdx.x;
  const int lane = t & 63;
  const int wave = t >> 6;
  __shared__ float2 pairs[4 * SEG];  // .x = e then p ; .y = j (int bits)
  __shared__ int counts[4];
  __shared__ float red[4];           // per-wave max
  __shared__ float red2[4];          // per-wave exp-sum
  __shared__ float fpart[4][FDIM];

  const float s1i = s1[i];
  const float4* __restrict__ arow = (const float4*)(adj + (size_t)i * N_NODES);
  float2* __restrict__ mypairs = pairs + wave * SEG;
  const unsigned long long lmask = (1ull << lane) - 1ull;

  // ---- scan: all 8 row-chunks in flight, index-only compaction ----
  float4 av[8];
#pragma unroll
  for (int it = 0; it < 8; ++it) av[it] = arow[it * 256 + t];
  int cbase = 0;
#pragma unroll
  for (int it = 0; it < 8; ++it) {
    const int j4 = it * 256 + t;
    float v[4] = {av[it].x, av[it].y, av[it].z, av[it].w};
#pragma unroll
    for (int c = 0; c < 4; ++c) {
      bool pred = (v[c] != 0.f);
      unsigned long long b = __ballot(pred);
      if (pred) {
        int pos = cbase + (int)__popcll(b & lmask);
        if (pos < SEG) ((int*)&mypairs[pos])[1] = j4 * 4 + c;
      }
      cbase += (int)__popcll(b);
    }
  }
  const int mycnt = cbase < SEG ? cbase : SEG;
  if (lane == 0) counts[wave] = mycnt;

  // ---- phase2: e from s2[j] gathers, wave max ----
  float lmax = -1e30f;
  for (int k = lane; k < mycnt; k += 64) {
    int j = ((const int*)&mypairs[k])[1];
    float e = s1i + s2[j];
    e = e > 0.f ? e : NEG_SLOPE * e;
    mypairs[k].x = e;
    lmax = fmaxf(lmax, e);
  }
  for (int off = 32; off; off >>= 1) lmax = fmaxf(lmax, __shfl_down(lmax, off));
  if (lane == 0) red[wave] = lmax;
  __syncthreads();
  const int cnt = counts[0] + counts[1] + counts[2] + counts[3];
  float m = fmaxf(fmaxf(red[0], red[1]), fmaxf(red[2], red[3]));
  if (cnt < N_NODES) m = fmaxf(m, 0.f);  // adj==0 entries contribute z=0
  const float em = __expf(-m);

  // ---- phase3: p = exp(e-m) once per pair, wave sum ----
  float lsum = 0.f;
  for (int k = lane; k < mycnt; k += 64) {
    float p = __expf(mypairs[k].x - m);
    mypairs[k].x = p;
    lsum += p;
  }
  for (int off = 32; off; off >>= 1) lsum += __shfl_down(lsum, off);
  if (lane == 0) red2[wave] = lsum;
  // no barrier needed: gather below reads only this wave's own segment

  // ---- gather: half-wave per pair, 4-deep unroll ----
  const int half = lane >> 5, lq = lane & 31;
  const float4* __restrict__ Wh4 = (const float4*)Wh;
  float ax = 0.f, ay = 0.f, az = 0.f, aw = 0.f;
  const int nit = (mycnt + 1) >> 1;
  int it = 0;
  for (; it + 3 < nit; it += 4) {
#pragma unroll
    for (int c = 0; c < 4; ++c) {
      int p = 2 * (it + c) + half;
      bool ok = p < mycnt;
      float2 pr = mypairs[ok ? p : 0];
      int j = ((const int*)&pr)[1];
      float4 v = Wh4[((size_t)j << 5) + lq];
      float w = ok ? pr.x - em : 0.f;
      ax += w * v.x; ay += w * v.y; az += w * v.z; aw += w * v.w;
    }
  }
  for (; it < nit; ++it) {
    int p = 2 * it + half;
    bool ok = p < mycnt;
    float2 pr = mypairs[ok ? p : 0];
    int j = ((const int*)&pr)[1];
    float4 v = Wh4[((size_t)j << 5) + lq];
    float w = ok ? pr.x - em : 0.f;
    ax += w * v.x; ay += w * v.y; az += w * v.z; aw += w * v.w;
  }
  // combine odd/even halves (same features, disjoint neighbor subsets)
  ax += __shfl_down(ax, 32);
  ay += __shfl_down(ay, 32);
  az += __shfl_down(az, 32);
  aw += __shfl_down(aw, 32);
  if (lane < 32)
    *(float4*)&fpart[wave][4 * lq] = make_float4(ax, ay, az, aw);
  __syncthreads();
  if (t < FDIM) {
    float l = red2[0] + red2[1] + red2[2] + red2[3]
              + (float)(N_NODES - cnt) * em;
    float o = (fpart[0][t] + fpart[1][t] + fpart[2][t] + fpart[3][t]
               + em * S[t]) / l;
    out[(size_t)i * FDIM + t] = o;
  }
}

extern "C" void kernel_launch(void* const* d_in, const int* in_sizes, int n_in,
                              void* d_out, int out_size, void* d_ws, size_t ws_size,
                              hipStream_t stream) {
  const float* h   = (const float*)d_in[0];
  const float* adj = (const float*)d_in[1];
  const float* W   = (const float*)d_in[2];
  const float* a   = (const float*)d_in[3];
  float* out = (float*)d_out;
  // workspace layout (fp32): Wh[N*F] | s1[N] | s2[N] | S[F]
  float* Wh = (float*)d_ws;
  float* s1 = Wh + (size_t)N_NODES * FDIM;
  float* s2 = s1 + N_NODES;
  float* S  = s2 + N_NODES;

  hipMemsetAsync(S, 0, FDIM * sizeof(float), stream);
  hipLaunchKernelGGL(wh_fused_kernel, dim3(N_NODES / 32), dim3(256), 0, stream,
                     h, W, Wh, S);
  hipLaunchKernelGGL(scores_kernel, dim3(N_NODES / 4), dim3(256), 0, stream,
                     Wh, a, s1, s2);
  hipLaunchKernelGGL(gat_row_kernel, dim3(N_NODES), dim3(256), 0, stream,
                     adj, Wh, s1, s2, S, out);
}